// Round 1
// baseline (1471.835 us; speedup 1.0000x reference)
//
#include <hip/hip_runtime.h>
#include <math.h>

#define NB 16
#define NT 512
#define NSZ 512
#define NH 8
#define NHD 64
#define NRPE 33
#define MAXR 16

#define C_D0 6.3f
#define C_STD 1.4f
#define C_GAMMA 2.0f

// ---------------------------------------------------------------------------
// C[M,N] = A[M,K] @ W[N,K]^T + bias[N]   (fp32, 64x64 tile, 4x4 microtile)
// ---------------------------------------------------------------------------
__global__ __launch_bounds__(256) void gemm_bt(
    const float* __restrict__ A, const float* __restrict__ W,
    const float* __restrict__ bias, float* __restrict__ C,
    int M, int N, int K)
{
    __shared__ float As[64][33];
    __shared__ float Bs[64][33];
    const int tid = threadIdx.x;
    const int m0 = blockIdx.x * 64;
    const int n0 = blockIdx.y * 64;
    const int tx = tid & 15;       // 0..15 -> 4 output cols
    const int ty = tid >> 4;       // 0..15 -> 4 output rows
    float acc[4][4] = {};

    for (int k0 = 0; k0 < K; k0 += 32) {
        // 64x32 tiles of A and W; 512 float4 loads each / 256 threads = 2 iters
        #pragma unroll
        for (int l = 0; l < 2; ++l) {
            int idx = tid + l * 256;      // float4 index 0..511
            int row = idx >> 3;           // 0..63
            int c4  = idx & 7;            // 0..7
            float4 av = *(const float4*)&A[(size_t)(m0 + row) * K + k0 + c4 * 4];
            As[row][c4*4+0] = av.x; As[row][c4*4+1] = av.y;
            As[row][c4*4+2] = av.z; As[row][c4*4+3] = av.w;
            float4 bv = *(const float4*)&W[(size_t)(n0 + row) * K + k0 + c4 * 4];
            Bs[row][c4*4+0] = bv.x; Bs[row][c4*4+1] = bv.y;
            Bs[row][c4*4+2] = bv.z; Bs[row][c4*4+3] = bv.w;
        }
        __syncthreads();
        #pragma unroll
        for (int kk = 0; kk < 32; ++kk) {
            float a[4], b[4];
            #pragma unroll
            for (int i = 0; i < 4; ++i) a[i] = As[ty*4+i][kk];
            #pragma unroll
            for (int j = 0; j < 4; ++j) b[j] = Bs[tx*4+j][kk];
            #pragma unroll
            for (int i = 0; i < 4; ++i)
                #pragma unroll
                for (int j = 0; j < 4; ++j)
                    acc[i][j] += a[i] * b[j];
        }
        __syncthreads();
    }
    #pragma unroll
    for (int i = 0; i < 4; ++i) {
        int r = m0 + ty*4 + i;
        #pragma unroll
        for (int j = 0; j < 4; ++j) {
            int c = n0 + tx*4 + j;
            C[(size_t)r * N + c] = acc[i][j] + bias[c];
        }
    }
}

// ---------------------------------------------------------------------------
// Fused depthwise conv1d(k=5, pad=2) over xn=key + scalar sigmoid gate blend.
// One block per (b,t); 128 threads x 4 channels each. QMODE also computes
// m_D[b,t] = D0 + 2*STD*tanh((gated_q . WmD + bmD)/GAMMA).
// ---------------------------------------------------------------------------
template <bool QMODE>
__global__ __launch_bounds__(128) void conv_gate(
    const float* __restrict__ xn,   // (B,T,SZ) raw key input
    float* __restrict__ p,          // (B*T,SZ) projected q/k/v, gated in-place
    const float* __restrict__ Wc,   // (SZ,5)
    const float* __restrict__ Wg,   // (2*SZ)
    const float* __restrict__ bg,   // (1)
    const float* __restrict__ WmD,  // (SZ) or null
    const float* __restrict__ bmD,  // (1) or null
    float* __restrict__ mD)         // (B*T) or null
{
    const int bt = blockIdx.x;
    const int b = bt / NT, t = bt % NT;
    const int tid = threadIdx.x;
    __shared__ float red[128];

    float qc[4], qp[4];
    float s = 0.f;
    #pragma unroll
    for (int i = 0; i < 4; ++i) {
        int c = tid + i * 128;
        float acc = 0.f;
        #pragma unroll
        for (int j = 0; j < 5; ++j) {
            int tt = t + j - 2;
            float x = (tt >= 0 && tt < NT) ? xn[((size_t)b*NT + tt)*NSZ + c] : 0.f;
            acc += x * Wc[c*5 + j];
        }
        qc[i] = acc;
        qp[i] = p[(size_t)bt * NSZ + c];
        s += qp[i] * Wg[c] + acc * Wg[NSZ + c];
    }
    red[tid] = s; __syncthreads();
    #pragma unroll
    for (int stride = 64; stride > 0; stride >>= 1) {
        if (tid < stride) red[tid] += red[tid + stride];
        __syncthreads();
    }
    float g = 1.f / (1.f + expf(-(red[0] + bg[0])));

    float og[4];
    #pragma unroll
    for (int i = 0; i < 4; ++i) {
        int c = tid + i * 128;
        og[i] = (1.f - g) * qp[i] + g * qc[i];
        p[(size_t)bt * NSZ + c] = og[i];
    }
    if (QMODE) {
        float sm = 0.f;
        #pragma unroll
        for (int i = 0; i < 4; ++i) sm += og[i] * WmD[tid + i * 128];
        __syncthreads();            // protect red reuse
        red[tid] = sm; __syncthreads();
        #pragma unroll
        for (int stride = 64; stride > 0; stride >>= 1) {
            if (tid < stride) red[tid] += red[tid + stride];
            __syncthreads();
        }
        if (tid == 0) {
            float off = red[0] + bmD[0];
            mD[bt] = C_D0 + 2.f * C_STD * tanhf(off / C_GAMMA);
        }
    }
}

// ---------------------------------------------------------------------------
// Attention: one 64-lane wave per (b,h,qpos).
// scores = qh.kh + (qh . rpe_k[rd]) - dist^2 * 2/m_D^2 ; mask -> -inf
// ctx = softmax(scores) @ (vh + rpe_v[rd])
// ---------------------------------------------------------------------------
__global__ __launch_bounds__(64) void attn_kernel(
    const float* __restrict__ qb, const float* __restrict__ kb,
    const float* __restrict__ vb, const float* __restrict__ mD,
    const int* __restrict__ mask, const float* __restrict__ rpe,
    float* __restrict__ ctx)
{
    const int qpos = blockIdx.x;
    const int h = blockIdx.y;
    const int b = blockIdx.z;
    const int lane = threadIdx.x;

    __shared__ float qs[NHD];
    __shared__ float ps[NT];
    __shared__ float qdr[NRPE];
    __shared__ float rv[NRPE][NHD];

    const size_t qrow = ((size_t)b*NT + qpos) * NSZ + h * NHD;
    qs[lane] = qb[qrow + lane] * 0.125f;   // 1/sqrt(64)
    for (int idx = lane; idx < NRPE * NHD; idx += 64)
        rv[idx / NHD][idx % NHD] = rpe[(idx / NHD) * 2 * NHD + NHD + (idx % NHD)];
    __syncthreads();
    if (lane < NRPE) {
        float sacc = 0.f;
        #pragma unroll
        for (int d = 0; d < NHD; ++d) sacc += qs[d] * rpe[lane * 2 * NHD + d];
        qdr[lane] = sacc;
    }
    __syncthreads();

    const float md = mD[b*NT + qpos];
    const float inv2 = 2.f / (md * md);

    float mx = -INFINITY;
    #pragma unroll
    for (int k = lane; k < NT; k += 64) {
        float sc;
        if (mask[b*NT + k]) {
            sc = -INFINITY;
        } else {
            const float4* kr = (const float4*)&kb[((size_t)b*NT + k) * NSZ + h * NHD];
            float dot = 0.f;
            #pragma unroll
            for (int d4 = 0; d4 < NHD/4; ++d4) {
                float4 kv = kr[d4];
                dot += qs[d4*4+0]*kv.x + qs[d4*4+1]*kv.y + qs[d4*4+2]*kv.z + qs[d4*4+3]*kv.w;
            }
            int di = k - qpos;
            int rd = min(max(di, -MAXR), MAXR) + MAXR;
            float dist = (float)(qpos - k);
            sc = dot + qdr[rd] - dist * dist * inv2;
        }
        ps[k] = sc;
        mx = fmaxf(mx, sc);
    }
    #pragma unroll
    for (int o = 32; o > 0; o >>= 1) mx = fmaxf(mx, __shfl_xor(mx, o, 64));

    float sum = 0.f;
    #pragma unroll
    for (int k = lane; k < NT; k += 64) {
        float pv = expf(ps[k] - mx);
        ps[k] = pv;
        sum += pv;
    }
    #pragma unroll
    for (int o = 32; o > 0; o >>= 1) sum += __shfl_xor(sum, o, 64);
    __syncthreads();

    const float inv_sum = 1.f / sum;
    const float* vcol = &vb[(size_t)b*NT*NSZ + h*NHD + lane];
    float acc = 0.f;
    for (int k = 0; k < NT; ++k) {
        float pv = ps[k];
        int rd = min(max(k - qpos, -MAXR), MAXR) + MAXR;
        acc += pv * (vcol[(size_t)k * NSZ] + rv[rd][lane]);
    }
    ctx[qrow + lane] = acc * inv_sum;
}

// ---------------------------------------------------------------------------
extern "C" void kernel_launch(void* const* d_in, const int* in_sizes, int n_in,
                              void* d_out, int out_size, void* d_ws, size_t ws_size,
                              hipStream_t stream) {
    const float* key   = (const float*)d_in[0];
    const float* value = (const float*)d_in[1];
    const float* query = (const float*)d_in[2];
    const int*   mask  = (const int*)d_in[3];
    const float* Wq  = (const float*)d_in[4];
    const float* bq  = (const float*)d_in[5];
    const float* Wk  = (const float*)d_in[6];
    const float* bk  = (const float*)d_in[7];
    const float* Wv  = (const float*)d_in[8];
    const float* bv  = (const float*)d_in[9];
    const float* Wcq = (const float*)d_in[10];
    const float* Wck = (const float*)d_in[11];
    const float* Wcv = (const float*)d_in[12];
    const float* Wgq = (const float*)d_in[13];
    const float* bgq = (const float*)d_in[14];
    const float* Wgk = (const float*)d_in[15];
    const float* bgk = (const float*)d_in[16];
    const float* Wgv = (const float*)d_in[17];
    const float* bgv = (const float*)d_in[18];
    const float* WmD = (const float*)d_in[19];
    const float* bmD = (const float*)d_in[20];
    const float* rpe = (const float*)d_in[21];
    const float* Wo  = (const float*)d_in[22];
    const float* bo  = (const float*)d_in[23];
    float* out = (float*)d_out;

    const size_t NTOK = (size_t)NB * NT;   // 8192
    float* ws  = (float*)d_ws;
    float* qb  = ws;
    float* kb  = qb  + NTOK * NSZ;
    float* vb  = kb  + NTOK * NSZ;
    float* ctx = vb  + NTOK * NSZ;
    float* mDb = ctx + NTOK * NSZ;

    dim3 gg(NTOK / 64, NSZ / 64);
    gemm_bt<<<gg, 256, 0, stream>>>(query, Wq, bq, qb, (int)NTOK, NSZ, NSZ);
    gemm_bt<<<gg, 256, 0, stream>>>(key,   Wk, bk, kb, (int)NTOK, NSZ, NSZ);
    gemm_bt<<<gg, 256, 0, stream>>>(value, Wv, bv, vb, (int)NTOK, NSZ, NSZ);

    conv_gate<true ><<<(int)NTOK, 128, 0, stream>>>(key, qb, Wcq, Wgq, bgq, WmD, bmD, mDb);
    conv_gate<false><<<(int)NTOK, 128, 0, stream>>>(key, kb, Wck, Wgk, bgk, nullptr, nullptr, nullptr);
    conv_gate<false><<<(int)NTOK, 128, 0, stream>>>(key, vb, Wcv, Wgv, bgv, nullptr, nullptr, nullptr);

    dim3 ga(NT, NH, NB);
    attn_kernel<<<ga, 64, 0, stream>>>(qb, kb, vb, mDb, mask, rpe, ctx);

    gemm_bt<<<gg, 256, 0, stream>>>(ctx, Wo, bo, out, (int)NTOK, NSZ, NSZ);
}

// Round 2
// 623.109 us; speedup vs baseline: 2.3621x; 2.3621x over previous
//
#include <hip/hip_runtime.h>
#include <math.h>

#define NB 16
#define NT 512
#define NSZ 512
#define NH 8
#define NHD 64
#define MAXR 16

#define C_D0 6.3f
#define C_STD 1.4f
#define C_GAMMA 2.0f

#define NEGINF (-1e30f)

// ---------------------------------------------------------------------------
// C[M,N] = A[M,K] @ W[N,K]^T + bias[N]   (fp32, 64x64 tile, 4x4 microtile)
// ---------------------------------------------------------------------------
__global__ __launch_bounds__(256) void gemm_bt(
    const float* __restrict__ A, const float* __restrict__ W,
    const float* __restrict__ bias, float* __restrict__ C,
    int M, int N, int K)
{
    __shared__ float As[64][33];
    __shared__ float Bs[64][33];
    const int tid = threadIdx.x;
    const int m0 = blockIdx.x * 64;
    const int n0 = blockIdx.y * 64;
    const int tx = tid & 15;
    const int ty = tid >> 4;
    float acc[4][4] = {};

    for (int k0 = 0; k0 < K; k0 += 32) {
        #pragma unroll
        for (int l = 0; l < 2; ++l) {
            int idx = tid + l * 256;
            int row = idx >> 3;
            int c4  = idx & 7;
            float4 av = *(const float4*)&A[(size_t)(m0 + row) * K + k0 + c4 * 4];
            As[row][c4*4+0] = av.x; As[row][c4*4+1] = av.y;
            As[row][c4*4+2] = av.z; As[row][c4*4+3] = av.w;
            float4 bv = *(const float4*)&W[(size_t)(n0 + row) * K + k0 + c4 * 4];
            Bs[row][c4*4+0] = bv.x; Bs[row][c4*4+1] = bv.y;
            Bs[row][c4*4+2] = bv.z; Bs[row][c4*4+3] = bv.w;
        }
        __syncthreads();
        #pragma unroll
        for (int kk = 0; kk < 32; ++kk) {
            float a[4], b[4];
            #pragma unroll
            for (int i = 0; i < 4; ++i) a[i] = As[ty*4+i][kk];
            #pragma unroll
            for (int j = 0; j < 4; ++j) b[j] = Bs[tx*4+j][kk];
            #pragma unroll
            for (int i = 0; i < 4; ++i)
                #pragma unroll
                for (int j = 0; j < 4; ++j)
                    acc[i][j] += a[i] * b[j];
        }
        __syncthreads();
    }
    #pragma unroll
    for (int i = 0; i < 4; ++i) {
        int r = m0 + ty*4 + i;
        #pragma unroll
        for (int j = 0; j < 4; ++j) {
            int c = n0 + tx*4 + j;
            C[(size_t)r * N + c] = acc[i][j] + bias[c];
        }
    }
}

// ---------------------------------------------------------------------------
// Fused depthwise conv1d(k=5) + scalar sigmoid gate (unchanged from R1)
// ---------------------------------------------------------------------------
template <bool QMODE>
__global__ __launch_bounds__(128) void conv_gate(
    const float* __restrict__ xn, float* __restrict__ p,
    const float* __restrict__ Wc, const float* __restrict__ Wg,
    const float* __restrict__ bg, const float* __restrict__ WmD,
    const float* __restrict__ bmD, float* __restrict__ mD)
{
    const int bt = blockIdx.x;
    const int b = bt / NT, t = bt % NT;
    const int tid = threadIdx.x;
    __shared__ float red[128];

    float qc[4], qp[4];
    float s = 0.f;
    #pragma unroll
    for (int i = 0; i < 4; ++i) {
        int c = tid + i * 128;
        float acc = 0.f;
        #pragma unroll
        for (int j = 0; j < 5; ++j) {
            int tt = t + j - 2;
            float x = (tt >= 0 && tt < NT) ? xn[((size_t)b*NT + tt)*NSZ + c] : 0.f;
            acc += x * Wc[c*5 + j];
        }
        qc[i] = acc;
        qp[i] = p[(size_t)bt * NSZ + c];
        s += qp[i] * Wg[c] + acc * Wg[NSZ + c];
    }
    red[tid] = s; __syncthreads();
    #pragma unroll
    for (int stride = 64; stride > 0; stride >>= 1) {
        if (tid < stride) red[tid] += red[tid + stride];
        __syncthreads();
    }
    float g = 1.f / (1.f + expf(-(red[0] + bg[0])));

    float og[4];
    #pragma unroll
    for (int i = 0; i < 4; ++i) {
        int c = tid + i * 128;
        og[i] = (1.f - g) * qp[i] + g * qc[i];
        p[(size_t)bt * NSZ + c] = og[i];
    }
    if (QMODE) {
        float sm = 0.f;
        #pragma unroll
        for (int i = 0; i < 4; ++i) sm += og[i] * WmD[tid + i * 128];
        __syncthreads();
        red[tid] = sm; __syncthreads();
        #pragma unroll
        for (int stride = 64; stride > 0; stride >>= 1) {
            if (tid < stride) red[tid] += red[tid + stride];
            __syncthreads();
        }
        if (tid == 0) {
            float off = red[0] + bmD[0];
            mD[bt] = C_D0 + 2.f * C_STD * tanhf(off / C_GAMMA);
        }
    }
}

// ---------------------------------------------------------------------------
// Tiled flash-style attention.
// Block = 256 threads, q-tile = 64, k-tile = 64, one block per (qtile, h, b).
// QK and PV as 4x4 fp32 microtiles from swizzled LDS.
// RPE-score via per-block qdr[q][rd] mini-GEMM; RPE-value via w[q][rd] buckets.
// ---------------------------------------------------------------------------
#define SW(dd)  ((((dd) >> 2) & 7) << 2)

__global__ __launch_bounds__(256) void attn_tiled(
    const float* __restrict__ qb, const float* __restrict__ kb,
    const float* __restrict__ vb, const float* __restrict__ mD,
    const int* __restrict__ mask, const float* __restrict__ rpe,
    float* __restrict__ ctx)
{
    __shared__ float Qt[64][64];     // [dd][q ^ SW(dd)], pre-scaled by 1/8
    __shared__ float KV[64][64];     // K-phase: [dd][k^SW(dd)]; V/rv-phase: [k][d]
    __shared__ float ps[64][64];     // [k][q ^ SW(k)]
    __shared__ float qdr[64][34];    // [q][rd]
    __shared__ float wbuf[64][34];   // [q][rd]
    __shared__ float inv2s[64];
    __shared__ int   msk[64];

    const int tid = threadIdx.x;
    const int tx = tid & 15;
    const int ty = tid >> 4;
    const int q0 = blockIdx.x * 64;
    const int h  = blockIdx.y;
    const int b  = blockIdx.z;

    // ---- prologue: stage Q (transposed, scaled), rpe_k (transposed), misc ----
    #pragma unroll
    for (int l2 = 0; l2 < 4; ++l2) {
        int idx = tid + l2 * 256;
        int r = idx >> 4, d4 = idx & 15;
        float4 v = *(const float4*)&qb[((size_t)(b*NT + q0 + r))*NSZ + h*NHD + d4*4];
        Qt[d4*4+0][r ^ SW(d4*4+0)] = v.x * 0.125f;
        Qt[d4*4+1][r ^ SW(d4*4+1)] = v.y * 0.125f;
        Qt[d4*4+2][r ^ SW(d4*4+2)] = v.z * 0.125f;
        Qt[d4*4+3][r ^ SW(d4*4+3)] = v.w * 0.125f;
    }
    for (int idx = tid; idx < 33*16; idx += 256) {
        int rr = idx >> 4, d4 = idx & 15;
        float4 v = *(const float4*)&rpe[rr*128 + d4*4];
        KV[d4*4+0][rr ^ SW(d4*4+0)] = v.x;
        KV[d4*4+1][rr ^ SW(d4*4+1)] = v.y;
        KV[d4*4+2][rr ^ SW(d4*4+2)] = v.z;
        KV[d4*4+3][rr ^ SW(d4*4+3)] = v.w;
    }
    if (tid < 64) {
        float md = mD[b*NT + q0 + tid];
        inv2s[tid] = 2.f / (md * md);
    }
    for (int idx = tid; idx < 64*34; idx += 256) ((float*)wbuf)[idx] = 0.f;
    __syncthreads();

    // ---- qdr[q][rd] = (q/8) . rpe_k[rd]  via one microtile pass ----
    {
        float s_[4][4] = {};
        #pragma unroll 8
        for (int dd = 0; dd < 64; ++dd) {
            float4 a  = *(const float4*)&Qt[dd][(ty*4) ^ SW(dd)];
            float4 bb = *(const float4*)&KV[dd][(tx*4) ^ SW(dd)];
            float av[4] = {a.x, a.y, a.z, a.w};
            float bv[4] = {bb.x, bb.y, bb.z, bb.w};
            #pragma unroll
            for (int i = 0; i < 4; ++i)
                #pragma unroll
                for (int j = 0; j < 4; ++j)
                    s_[i][j] += av[i] * bv[j];
        }
        #pragma unroll
        for (int j = 0; j < 4; ++j) {
            int rr = tx*4 + j;
            if (rr < 33) {
                #pragma unroll
                for (int i = 0; i < 4; ++i) qdr[ty*4+i][rr] = s_[i][j];
            }
        }
    }
    __syncthreads();

    // ---- main k-tile loop ----
    float O[4][4] = {};
    float m_i[4] = {NEGINF, NEGINF, NEGINF, NEGINF};
    float l_i[4] = {};

    for (int kt = 0; kt < 8; ++kt) {
        const int kbase = kt * 64;
        if (mask[b*NT + kbase]) continue;   // fully-masked tile (mask monotone)

        float4 kreg[4], vreg[4];
        #pragma unroll
        for (int l2 = 0; l2 < 4; ++l2) {
            int idx = tid + l2 * 256;
            int r = idx >> 4, d4 = idx & 15;
            size_t goff = ((size_t)(b*NT + kbase + r))*NSZ + h*NHD + d4*4;
            kreg[l2] = *(const float4*)&kb[goff];
            vreg[l2] = *(const float4*)&vb[goff];
        }
        if (tid < 64) msk[tid] = mask[b*NT + kbase + tid];
        __syncthreads();   // (A) prev PV done reading KV
        #pragma unroll
        for (int l2 = 0; l2 < 4; ++l2) {
            int idx = tid + l2 * 256;
            int r = idx >> 4, d4 = idx & 15;
            KV[d4*4+0][r ^ SW(d4*4+0)] = kreg[l2].x;
            KV[d4*4+1][r ^ SW(d4*4+1)] = kreg[l2].y;
            KV[d4*4+2][r ^ SW(d4*4+2)] = kreg[l2].z;
            KV[d4*4+3][r ^ SW(d4*4+3)] = kreg[l2].w;
        }
        __syncthreads();   // (B) K tile visible

        // QK^T microtile
        float s_[4][4] = {};
        #pragma unroll 8
        for (int dd = 0; dd < 64; ++dd) {
            float4 a  = *(const float4*)&Qt[dd][(ty*4) ^ SW(dd)];
            float4 bb = *(const float4*)&KV[dd][(tx*4) ^ SW(dd)];
            float av[4] = {a.x, a.y, a.z, a.w};
            float bv[4] = {bb.x, bb.y, bb.z, bb.w};
            #pragma unroll
            for (int i = 0; i < 4; ++i)
                #pragma unroll
                for (int j = 0; j < 4; ++j)
                    s_[i][j] += av[i] * bv[j];
        }

        // softmax + bucket bookkeeping
        const bool leftfar  = (kbase + 79 <= q0);
        const bool rightfar = (kbase >= q0 + 79);
        const bool mid = !leftfar && !rightfar;

        float p_[4][4], alpha[4], rsum_[4], ls_[4], rs_[4];
        bool anyresc = false;
        #pragma unroll
        for (int i = 0; i < 4; ++i) {
            int qg = q0 + ty*4 + i;
            float iv = inv2s[ty*4+i];
            float qdrf = leftfar ? qdr[ty*4+i][0] : (rightfar ? qdr[ty*4+i][32] : 0.f);
            float sc_[4];
            float mxl = NEGINF;
            #pragma unroll
            for (int j = 0; j < 4; ++j) {
                int kg = kbase + tx*4 + j;
                float sc;
                if (msk[tx*4+j]) {
                    sc = NEGINF;
                } else {
                    float dist = (float)(qg - kg);
                    float r = qdrf;
                    if (mid) {
                        int rd = min(max(kg - qg, -MAXR), MAXR) + MAXR;
                        r = qdr[ty*4+i][rd];
                    }
                    sc = s_[i][j] + r - dist * dist * iv;
                }
                sc_[j] = sc;
                mxl = fmaxf(mxl, sc);
            }
            #pragma unroll
            for (int m2 = 1; m2 < 16; m2 <<= 1)
                mxl = fmaxf(mxl, __shfl_xor(mxl, m2, 64));
            float mnew = fmaxf(m_i[i], mxl);
            alpha[i] = expf(m_i[i] - mnew);
            m_i[i] = mnew;
            float rsum = 0.f, ls = 0.f, rs = 0.f;
            #pragma unroll
            for (int j = 0; j < 4; ++j) {
                float pv = expf(sc_[j] - mnew);
                p_[i][j] = pv;
                rsum += pv;
                if (mid) {
                    int kg = kbase + tx*4 + j;
                    if (kg <= qg - MAXR) ls += pv;
                    else if (kg >= qg + MAXR) rs += pv;
                }
            }
            #pragma unroll
            for (int m2 = 1; m2 < 16; m2 <<= 1) {
                rsum += __shfl_xor(rsum, m2, 64);
                if (mid) { ls += __shfl_xor(ls, m2, 64); rs += __shfl_xor(rs, m2, 64); }
            }
            l_i[i] = l_i[i] * alpha[i] + rsum;
            rsum_[i] = rsum; ls_[i] = ls; rs_[i] = rs;
            anyresc |= (alpha[i] != 1.0f);
            #pragma unroll
            for (int j = 0; j < 4; ++j) O[i][j] *= alpha[i];
        }

        // w rescale, then this tile's contributions
        if (anyresc) {
            for (int c = tx; c < 33; c += 16) {
                #pragma unroll
                for (int i = 0; i < 4; ++i) wbuf[ty*4+i][c] *= alpha[i];
            }
        }
        if (leftfar) {
            if (tx == 0) {
                #pragma unroll
                for (int i = 0; i < 4; ++i) wbuf[ty*4+i][0] += rsum_[i];
            }
        } else if (rightfar) {
            if (tx == 0) {
                #pragma unroll
                for (int i = 0; i < 4; ++i) wbuf[ty*4+i][32] += rsum_[i];
            }
        } else {
            if (tx == 0) {
                #pragma unroll
                for (int i = 0; i < 4; ++i) {
                    wbuf[ty*4+i][0]  += ls_[i];
                    wbuf[ty*4+i][32] += rs_[i];
                }
            }
            #pragma unroll
            for (int i = 0; i < 4; ++i) {
                int qg = q0 + ty*4 + i;
                #pragma unroll
                for (int j = 0; j < 4; ++j) {
                    int d = kbase + tx*4 + j - qg;
                    if (d > -MAXR && d < MAXR) wbuf[ty*4+i][d + MAXR] += p_[i][j];
                }
            }
        }

        // write p to LDS (vectorized over i)
        #pragma unroll
        for (int j = 0; j < 4; ++j) {
            int kq = tx*4 + j;
            float4 pc = {p_[0][j], p_[1][j], p_[2][j], p_[3][j]};
            *(float4*)&ps[kq][(ty*4) ^ SW(kq)] = pc;
        }
        __syncthreads();   // (C) ps visible; QK done reading KV
        #pragma unroll
        for (int l2 = 0; l2 < 4; ++l2) {
            int idx = tid + l2 * 256;
            int r = idx >> 4, d4 = idx & 15;
            *(float4*)&KV[r][d4*4] = vreg[l2];
        }
        __syncthreads();   // (D) V tile visible

        // PV microtile
        #pragma unroll 4
        for (int k = 0; k < 64; ++k) {
            float4 pv = *(const float4*)&ps[k][(ty*4) ^ SW(k)];
            float4 vv = *(const float4*)&KV[k][tx*4];
            float pa[4] = {pv.x, pv.y, pv.z, pv.w};
            float va[4] = {vv.x, vv.y, vv.z, vv.w};
            #pragma unroll
            for (int i = 0; i < 4; ++i)
                #pragma unroll
                for (int j = 0; j < 4; ++j)
                    O[i][j] += pa[i] * va[j];
        }
        __syncthreads();   // (E) PV done; KV free for next tile
    }

    // ---- epilogue: O += w @ rpe_v ; write ctx ----
    for (int idx = tid; idx < 33*16; idx += 256) {
        int rr = idx >> 4, d4 = idx & 15;
        *(float4*)&KV[rr][d4*4] = *(const float4*)&rpe[rr*128 + NHD + d4*4];
    }
    __syncthreads();
    #pragma unroll 4
    for (int rd = 0; rd < 33; ++rd) {
        float4 rvv = *(const float4*)&KV[rd][tx*4];
        float rva[4] = {rvv.x, rvv.y, rvv.z, rvv.w};
        #pragma unroll
        for (int i = 0; i < 4; ++i) {
            float wq = wbuf[ty*4+i][rd];
            #pragma unroll
            for (int j = 0; j < 4; ++j) O[i][j] += wq * rva[j];
        }
    }
    #pragma unroll
    for (int i = 0; i < 4; ++i) {
        float invl = 1.f / l_i[i];
        float4 o = {O[i][0]*invl, O[i][1]*invl, O[i][2]*invl, O[i][3]*invl};
        *(float4*)&ctx[((size_t)(b*NT + q0 + ty*4 + i))*NSZ + h*NHD + tx*4] = o;
    }
}

// ---------------------------------------------------------------------------
extern "C" void kernel_launch(void* const* d_in, const int* in_sizes, int n_in,
                              void* d_out, int out_size, void* d_ws, size_t ws_size,
                              hipStream_t stream) {
    const float* key   = (const float*)d_in[0];
    const float* value = (const float*)d_in[1];
    const float* query = (const float*)d_in[2];
    const int*   mask  = (const int*)d_in[3];
    const float* Wq  = (const float*)d_in[4];
    const float* bq  = (const float*)d_in[5];
    const float* Wk  = (const float*)d_in[6];
    const float* bk  = (const float*)d_in[7];
    const float* Wv  = (const float*)d_in[8];
    const float* bv  = (const float*)d_in[9];
    const float* Wcq = (const float*)d_in[10];
    const float* Wck = (const float*)d_in[11];
    const float* Wcv = (const float*)d_in[12];
    const float* Wgq = (const float*)d_in[13];
    const float* bgq = (const float*)d_in[14];
    const float* Wgk = (const float*)d_in[15];
    const float* bgk = (const float*)d_in[16];
    const float* Wgv = (const float*)d_in[17];
    const float* bgv = (const float*)d_in[18];
    const float* WmD = (const float*)d_in[19];
    const float* bmD = (const float*)d_in[20];
    const float* rpe = (const float*)d_in[21];
    const float* Wo  = (const float*)d_in[22];
    const float* bo  = (const float*)d_in[23];
    float* out = (float*)d_out;

    const size_t NTOK = (size_t)NB * NT;
    float* ws  = (float*)d_ws;
    float* qb  = ws;
    float* kb  = qb  + NTOK * NSZ;
    float* vb  = kb  + NTOK * NSZ;
    float* ctx = vb  + NTOK * NSZ;
    float* mDb = ctx + NTOK * NSZ;

    dim3 gg(NTOK / 64, NSZ / 64);
    gemm_bt<<<gg, 256, 0, stream>>>(query, Wq, bq, qb, (int)NTOK, NSZ, NSZ);
    gemm_bt<<<gg, 256, 0, stream>>>(key,   Wk, bk, kb, (int)NTOK, NSZ, NSZ);
    gemm_bt<<<gg, 256, 0, stream>>>(value, Wv, bv, vb, (int)NTOK, NSZ, NSZ);

    conv_gate<true ><<<(int)NTOK, 128, 0, stream>>>(key, qb, Wcq, Wgq, bgq, WmD, bmD, mDb);
    conv_gate<false><<<(int)NTOK, 128, 0, stream>>>(key, kb, Wck, Wgk, bgk, nullptr, nullptr, nullptr);
    conv_gate<false><<<(int)NTOK, 128, 0, stream>>>(key, vb, Wcv, Wgv, bgv, nullptr, nullptr, nullptr);

    dim3 ga(NT / 64, NH, NB);
    attn_tiled<<<ga, 256, 0, stream>>>(qb, kb, vb, mDb, mask, rpe, ctx);

    gemm_bt<<<gg, 256, 0, stream>>>(ctx, Wo, bo, out, (int)NTOK, NSZ, NSZ);
}

// Round 3
// 346.795 us; speedup vs baseline: 4.2441x; 1.7968x over previous
//
#include <hip/hip_runtime.h>
#include <math.h>

#define NB 16
#define NT 512
#define NSZ 512
#define NH 8
#define NHD 64
#define MAXR 16

#define C_D0 6.3f
#define C_STD 1.4f
#define C_GAMMA 2.0f

#define NEGINF (-1e30f)

typedef __attribute__((ext_vector_type(8))) short bf16x8;
typedef __attribute__((ext_vector_type(4))) float f32x4;
typedef __attribute__((ext_vector_type(8))) unsigned short u16x8;
typedef __attribute__((ext_vector_type(4))) unsigned short u16x4;

__device__ __forceinline__ unsigned short f2b(float f) {
    union { float f; unsigned int u; } c; c.f = f;
    unsigned int u = c.u + 0x7FFFu + ((c.u >> 16) & 1u);
    return (unsigned short)(u >> 16);
}
__device__ __forceinline__ float b2f(unsigned short h) {
    union { unsigned int u; float f; } c; c.u = ((unsigned int)h) << 16;
    return c.f;
}

#define GL2LDS(gp, lp) __builtin_amdgcn_global_load_lds( \
    (const __attribute__((address_space(1))) void*)(gp), \
    (__attribute__((address_space(3))) void*)(lp), 16, 0, 0)

// ---------------------------------------------------------------------------
// fp32 -> bf16 converts
// ---------------------------------------------------------------------------
__global__ __launch_bounds__(256) void cvt3_bf16(
    const float* __restrict__ s0, const float* __restrict__ s1,
    const float* __restrict__ s2, unsigned short* __restrict__ d0,
    unsigned short* __restrict__ d1, unsigned short* __restrict__ d2, int n)
{
    const float* s = blockIdx.y == 0 ? s0 : (blockIdx.y == 1 ? s1 : s2);
    unsigned short* d = blockIdx.y == 0 ? d0 : (blockIdx.y == 1 ? d1 : d2);
    int i = (blockIdx.x * 256 + threadIdx.x) * 8;
    if (i >= n) return;
    float4 a = *(const float4*)&s[i];
    float4 b = *(const float4*)&s[i + 4];
    u16x8 v;
    v[0]=f2b(a.x); v[1]=f2b(a.y); v[2]=f2b(a.z); v[3]=f2b(a.w);
    v[4]=f2b(b.x); v[5]=f2b(b.y); v[6]=f2b(b.z); v[7]=f2b(b.w);
    *(u16x8*)&d[i] = v;
}

__global__ __launch_bounds__(256) void cvt4_bf16(
    const float* __restrict__ s0, const float* __restrict__ s1,
    const float* __restrict__ s2, const float* __restrict__ s3,
    unsigned short* __restrict__ d0, unsigned short* __restrict__ d1,
    unsigned short* __restrict__ d2, unsigned short* __restrict__ d3, int n)
{
    const float* s; unsigned short* d;
    switch (blockIdx.y) {
        case 0: s = s0; d = d0; break;
        case 1: s = s1; d = d1; break;
        case 2: s = s2; d = d2; break;
        default: s = s3; d = d3; break;
    }
    int i = (blockIdx.x * 256 + threadIdx.x) * 8;
    if (i >= n) return;
    float4 a = *(const float4*)&s[i];
    float4 b = *(const float4*)&s[i + 4];
    u16x8 v;
    v[0]=f2b(a.x); v[1]=f2b(a.y); v[2]=f2b(a.z); v[3]=f2b(a.w);
    v[4]=f2b(b.x); v[5]=f2b(b.y); v[6]=f2b(b.z); v[7]=f2b(b.w);
    *(u16x8*)&d[i] = v;
}

// ---------------------------------------------------------------------------
// bf16 MFMA GEMM: C[M,N] = A[M,K] @ W[N,K]^T + bias   (m97 structure)
// 128x128 tile, BK=32, 4 waves (2x2), wave tile 64x64 = 4x4 frags 16x16x32.
// ---------------------------------------------------------------------------
template <bool BF16OUT>
__global__ __launch_bounds__(256) void gemm_mfma(
    const unsigned short* __restrict__ A, const unsigned short* __restrict__ W,
    const float* __restrict__ bias, void* __restrict__ Cout,
    int M, int N, int K)
{
    __shared__ unsigned short Al[128 * 32];
    __shared__ unsigned short Bl[128 * 32];
    const int tid = threadIdx.x;
    const int m0 = blockIdx.x * 128;
    const int n0 = blockIdx.y * 128;
    const int w = tid >> 6;
    const int lane = tid & 63;
    const int wm = (w >> 1) * 64, wn = (w & 1) * 64;
    const int fr = lane & 15;
    const int fk = lane >> 4;

    f32x4 acc[4][4] = {};

    for (int k0 = 0; k0 < K; k0 += 32) {
        #pragma unroll
        for (int p = 0; p < 2; ++p) {
            int s = tid + p * 256;          // 16B slot
            int row = s >> 2, cb = s & 3;
            GL2LDS(&A[(size_t)(m0 + row) * K + k0 + cb * 8], &Al[s * 8]);
            GL2LDS(&W[(size_t)(n0 + row) * K + k0 + cb * 8], &Bl[s * 8]);
        }
        __syncthreads();
        bf16x8 af[4], bf[4];
        #pragma unroll
        for (int mf = 0; mf < 4; ++mf)
            af[mf] = *(const bf16x8*)&Al[(wm + mf * 16 + fr) * 32 + fk * 8];
        #pragma unroll
        for (int nf = 0; nf < 4; ++nf)
            bf[nf] = *(const bf16x8*)&Bl[(wn + nf * 16 + fr) * 32 + fk * 8];
        #pragma unroll
        for (int mf = 0; mf < 4; ++mf)
            #pragma unroll
            for (int nf = 0; nf < 4; ++nf)
                acc[mf][nf] = __builtin_amdgcn_mfma_f32_16x16x32_bf16(
                    af[mf], bf[nf], acc[mf][nf], 0, 0, 0);
        __syncthreads();
    }
    // D[row=(lane>>4)*4+r][col=lane&15]
    #pragma unroll
    for (int mf = 0; mf < 4; ++mf) {
        #pragma unroll
        for (int nf = 0; nf < 4; ++nf) {
            int col = n0 + wn + nf * 16 + fr;
            float bv = bias[col];
            #pragma unroll
            for (int r = 0; r < 4; ++r) {
                int rowg = m0 + wm + mf * 16 + fk * 4 + r;
                float val = acc[mf][nf][r] + bv;
                if (BF16OUT)
                    ((unsigned short*)Cout)[(size_t)rowg * N + col] = f2b(val);
                else
                    ((float*)Cout)[(size_t)rowg * N + col] = val;
            }
        }
    }
}

// ---------------------------------------------------------------------------
// Fused depthwise conv1d(k=5) + scalar sigmoid gate; bf16 in/out, fp32 math.
// ---------------------------------------------------------------------------
template <bool QMODE>
__global__ __launch_bounds__(128) void conv_gate(
    const unsigned short* __restrict__ xn,   // bf16 key
    unsigned short* __restrict__ p,          // bf16 projected, gated in-place
    const float* __restrict__ Wc, const float* __restrict__ Wg,
    const float* __restrict__ bg, const float* __restrict__ WmD,
    const float* __restrict__ bmD, float* __restrict__ mD)
{
    const int bt = blockIdx.x;
    const int b = bt / NT, t = bt % NT;
    const int tid = threadIdx.x;
    __shared__ float red[128];

    float qc[4], qp_[4];
    float s = 0.f;
    #pragma unroll
    for (int i = 0; i < 4; ++i) {
        int c = tid + i * 128;
        float acc = 0.f;
        #pragma unroll
        for (int j = 0; j < 5; ++j) {
            int tt = t + j - 2;
            float x = (tt >= 0 && tt < NT) ? b2f(xn[((size_t)b*NT + tt)*NSZ + c]) : 0.f;
            acc += x * Wc[c*5 + j];
        }
        qc[i] = acc;
        qp_[i] = b2f(p[(size_t)bt * NSZ + c]);
        s += qp_[i] * Wg[c] + acc * Wg[NSZ + c];
    }
    red[tid] = s; __syncthreads();
    #pragma unroll
    for (int stride = 64; stride > 0; stride >>= 1) {
        if (tid < stride) red[tid] += red[tid + stride];
        __syncthreads();
    }
    float g = 1.f / (1.f + expf(-(red[0] + bg[0])));

    float og[4];
    #pragma unroll
    for (int i = 0; i < 4; ++i) {
        int c = tid + i * 128;
        og[i] = (1.f - g) * qp_[i] + g * qc[i];
        p[(size_t)bt * NSZ + c] = f2b(og[i]);
    }
    if (QMODE) {
        float sm = 0.f;
        #pragma unroll
        for (int i = 0; i < 4; ++i) sm += og[i] * WmD[tid + i * 128];
        __syncthreads();
        red[tid] = sm; __syncthreads();
        #pragma unroll
        for (int stride = 64; stride > 0; stride >>= 1) {
            if (tid < stride) red[tid] += red[tid + stride];
            __syncthreads();
        }
        if (tid == 0) {
            float off = red[0] + bmD[0];
            mD[bt] = C_D0 + 2.f * C_STD * tanhf(off / C_GAMMA);
        }
    }
}

// ---------------------------------------------------------------------------
// Tiled flash-style attention, bf16 inputs (fp32 compute), bf16 ctx out.
// ---------------------------------------------------------------------------
#define SW(dd)  ((((dd) >> 2) & 7) << 2)

__global__ __launch_bounds__(256) void attn_tiled(
    const unsigned short* __restrict__ qb, const unsigned short* __restrict__ kb,
    const unsigned short* __restrict__ vb, const float* __restrict__ mD,
    const int* __restrict__ mask, const float* __restrict__ rpe,
    unsigned short* __restrict__ ctx)
{
    __shared__ float Qt[64][64];     // [dd][q ^ SW(dd)], pre-scaled by 1/8
    __shared__ float KV[64][64];     // K-phase: [dd][k^SW(dd)]; V-phase: [k][d]
    __shared__ float ps[64][64];     // [k][q ^ SW(k)]
    __shared__ float qdr[64][34];
    __shared__ float wbuf[64][34];
    __shared__ float inv2s[64];
    __shared__ int   msk[64];

    const int tid = threadIdx.x;
    const int tx = tid & 15;
    const int ty = tid >> 4;
    const int q0 = blockIdx.x * 64;
    const int h  = blockIdx.y;
    const int b  = blockIdx.z;

    // ---- prologue ----
    #pragma unroll
    for (int p = 0; p < 2; ++p) {
        int u = tid + p * 256;
        int r = u >> 3, d8 = u & 7;
        u16x8 v = *(const u16x8*)&qb[((size_t)(b*NT + q0 + r))*NSZ + h*NHD + d8*8];
        #pragma unroll
        for (int j = 0; j < 8; ++j) {
            int d = d8*8 + j;
            Qt[d][r ^ SW(d)] = b2f(v[j]) * 0.125f;
        }
    }
    for (int idx = tid; idx < 33*16; idx += 256) {
        int rr = idx >> 4, d4 = idx & 15;
        float4 v = *(const float4*)&rpe[rr*128 + d4*4];
        KV[d4*4+0][rr ^ SW(d4*4+0)] = v.x;
        KV[d4*4+1][rr ^ SW(d4*4+1)] = v.y;
        KV[d4*4+2][rr ^ SW(d4*4+2)] = v.z;
        KV[d4*4+3][rr ^ SW(d4*4+3)] = v.w;
    }
    if (tid < 64) {
        float md = mD[b*NT + q0 + tid];
        inv2s[tid] = 2.f / (md * md);
    }
    for (int idx = tid; idx < 64*34; idx += 256) ((float*)wbuf)[idx] = 0.f;
    __syncthreads();

    // ---- qdr[q][rd] = (q/8) . rpe_k[rd] ----
    {
        float s_[4][4] = {};
        #pragma unroll 8
        for (int dd = 0; dd < 64; ++dd) {
            float4 a  = *(const float4*)&Qt[dd][(ty*4) ^ SW(dd)];
            float4 bb = *(const float4*)&KV[dd][(tx*4) ^ SW(dd)];
            float av[4] = {a.x, a.y, a.z, a.w};
            float bv[4] = {bb.x, bb.y, bb.z, bb.w};
            #pragma unroll
            for (int i = 0; i < 4; ++i)
                #pragma unroll
                for (int j = 0; j < 4; ++j)
                    s_[i][j] += av[i] * bv[j];
        }
        #pragma unroll
        for (int j = 0; j < 4; ++j) {
            int rr = tx*4 + j;
            if (rr < 33) {
                #pragma unroll
                for (int i = 0; i < 4; ++i) qdr[ty*4+i][rr] = s_[i][j];
            }
        }
    }
    __syncthreads();

    // ---- main k-tile loop ----
    float O[4][4] = {};
    float m_i[4] = {NEGINF, NEGINF, NEGINF, NEGINF};
    float l_i[4] = {};

    for (int kt = 0; kt < 8; ++kt) {
        const int kbase = kt * 64;
        if (mask[b*NT + kbase]) continue;

        u16x8 kreg[2], vreg[2];
        #pragma unroll
        for (int p = 0; p < 2; ++p) {
            int u = tid + p * 256;
            int r = u >> 3, d8 = u & 7;
            size_t goff = ((size_t)(b*NT + kbase + r))*NSZ + h*NHD + d8*8;
            kreg[p] = *(const u16x8*)&kb[goff];
            vreg[p] = *(const u16x8*)&vb[goff];
        }
        if (tid < 64) msk[tid] = mask[b*NT + kbase + tid];
        __syncthreads();   // (A)
        #pragma unroll
        for (int p = 0; p < 2; ++p) {
            int u = tid + p * 256;
            int r = u >> 3, d8 = u & 7;
            #pragma unroll
            for (int j = 0; j < 8; ++j) {
                int d = d8*8 + j;
                KV[d][r ^ SW(d)] = b2f(kreg[p][j]);
            }
        }
        __syncthreads();   // (B)

        float s_[4][4] = {};
        #pragma unroll 8
        for (int dd = 0; dd < 64; ++dd) {
            float4 a  = *(const float4*)&Qt[dd][(ty*4) ^ SW(dd)];
            float4 bb = *(const float4*)&KV[dd][(tx*4) ^ SW(dd)];
            float av[4] = {a.x, a.y, a.z, a.w};
            float bv[4] = {bb.x, bb.y, bb.z, bb.w};
            #pragma unroll
            for (int i = 0; i < 4; ++i)
                #pragma unroll
                for (int j = 0; j < 4; ++j)
                    s_[i][j] += av[i] * bv[j];
        }

        const bool leftfar  = (kbase + 79 <= q0);
        const bool rightfar = (kbase >= q0 + 79);
        const bool mid = !leftfar && !rightfar;

        float p_[4][4], alpha[4], rsum_[4], ls_[4], rs_[4];
        bool anyresc = false;
        #pragma unroll
        for (int i = 0; i < 4; ++i) {
            int qg = q0 + ty*4 + i;
            float iv = inv2s[ty*4+i];
            float qdrf = leftfar ? qdr[ty*4+i][0] : (rightfar ? qdr[ty*4+i][32] : 0.f);
            float sc_[4];
            float mxl = NEGINF;
            #pragma unroll
            for (int j = 0; j < 4; ++j) {
                int kg = kbase + tx*4 + j;
                float sc;
                if (msk[tx*4+j]) {
                    sc = NEGINF;
                } else {
                    float dist = (float)(qg - kg);
                    float r = qdrf;
                    if (mid) {
                        int rd = min(max(kg - qg, -MAXR), MAXR) + MAXR;
                        r = qdr[ty*4+i][rd];
                    }
                    sc = s_[i][j] + r - dist * dist * iv;
                }
                sc_[j] = sc;
                mxl = fmaxf(mxl, sc);
            }
            #pragma unroll
            for (int m2 = 1; m2 < 16; m2 <<= 1)
                mxl = fmaxf(mxl, __shfl_xor(mxl, m2, 64));
            float mnew = fmaxf(m_i[i], mxl);
            alpha[i] = expf(m_i[i] - mnew);
            m_i[i] = mnew;
            float rsum = 0.f, ls = 0.f, rs = 0.f;
            #pragma unroll
            for (int j = 0; j < 4; ++j) {
                float pv = expf(sc_[j] - mnew);
                p_[i][j] = pv;
                rsum += pv;
                if (mid) {
                    int kg = kbase + tx*4 + j;
                    if (kg <= qg - MAXR) ls += pv;
                    else if (kg >= qg + MAXR) rs += pv;
                }
            }
            #pragma unroll
            for (int m2 = 1; m2 < 16; m2 <<= 1) {
                rsum += __shfl_xor(rsum, m2, 64);
                if (mid) { ls += __shfl_xor(ls, m2, 64); rs += __shfl_xor(rs, m2, 64); }
            }
            l_i[i] = l_i[i] * alpha[i] + rsum;
            rsum_[i] = rsum; ls_[i] = ls; rs_[i] = rs;
            anyresc |= (alpha[i] != 1.0f);
            #pragma unroll
            for (int j = 0; j < 4; ++j) O[i][j] *= alpha[i];
        }

        if (anyresc) {
            for (int c = tx; c < 33; c += 16) {
                #pragma unroll
                for (int i = 0; i < 4; ++i) wbuf[ty*4+i][c] *= alpha[i];
            }
        }
        if (leftfar) {
            if (tx == 0) {
                #pragma unroll
                for (int i = 0; i < 4; ++i) wbuf[ty*4+i][0] += rsum_[i];
            }
        } else if (rightfar) {
            if (tx == 0) {
                #pragma unroll
                for (int i = 0; i < 4; ++i) wbuf[ty*4+i][32] += rsum_[i];
            }
        } else {
            if (tx == 0) {
                #pragma unroll
                for (int i = 0; i < 4; ++i) {
                    wbuf[ty*4+i][0]  += ls_[i];
                    wbuf[ty*4+i][32] += rs_[i];
                }
            }
            #pragma unroll
            for (int i = 0; i < 4; ++i) {
                int qg = q0 + ty*4 + i;
                #pragma unroll
                for (int j = 0; j < 4; ++j) {
                    int d = kbase + tx*4 + j - qg;
                    if (d > -MAXR && d < MAXR) wbuf[ty*4+i][d + MAXR] += p_[i][j];
                }
            }
        }

        #pragma unroll
        for (int j = 0; j < 4; ++j) {
            int kq = tx*4 + j;
            float4 pc = {p_[0][j], p_[1][j], p_[2][j], p_[3][j]};
            *(float4*)&ps[kq][(ty*4) ^ SW(kq)] = pc;
        }
        __syncthreads();   // (C)
        #pragma unroll
        for (int p = 0; p < 2; ++p) {
            int u = tid + p * 256;
            int r = u >> 3, d8 = u & 7;
            #pragma unroll
            for (int j = 0; j < 8; ++j)
                KV[r][d8*8 + j] = b2f(vreg[p][j]);
        }
        __syncthreads();   // (D)

        #pragma unroll 4
        for (int k = 0; k < 64; ++k) {
            float4 pv = *(const float4*)&ps[k][(ty*4) ^ SW(k)];
            float4 vv = *(const float4*)&KV[k][tx*4];
            float pa[4] = {pv.x, pv.y, pv.z, pv.w};
            float va[4] = {vv.x, vv.y, vv.z, vv.w};
            #pragma unroll
            for (int i = 0; i < 4; ++i)
                #pragma unroll
                for (int j = 0; j < 4; ++j)
                    O[i][j] += pa[i] * va[j];
        }
        __syncthreads();   // (E)
    }

    // ---- epilogue: O += w @ rpe_v ; write ctx (bf16) ----
    for (int idx = tid; idx < 33*16; idx += 256) {
        int rr = idx >> 4, d4 = idx & 15;
        *(float4*)&KV[rr][d4*4] = *(const float4*)&rpe[rr*128 + NHD + d4*4];
    }
    __syncthreads();
    #pragma unroll 4
    for (int rd = 0; rd < 33; ++rd) {
        float4 rvv = *(const float4*)&KV[rd][tx*4];
        float rva[4] = {rvv.x, rvv.y, rvv.z, rvv.w};
        #pragma unroll
        for (int i = 0; i < 4; ++i) {
            float wq = wbuf[ty*4+i][rd];
            #pragma unroll
            for (int j = 0; j < 4; ++j) O[i][j] += wq * rva[j];
        }
    }
    #pragma unroll
    for (int i = 0; i < 4; ++i) {
        float invl = 1.f / l_i[i];
        u16x4 o;
        o[0] = f2b(O[i][0]*invl); o[1] = f2b(O[i][1]*invl);
        o[2] = f2b(O[i][2]*invl); o[3] = f2b(O[i][3]*invl);
        *(u16x4*)&ctx[((size_t)(b*NT + q0 + ty*4 + i))*NSZ + h*NHD + tx*4] = o;
    }
}

// ---------------------------------------------------------------------------
extern "C" void kernel_launch(void* const* d_in, const int* in_sizes, int n_in,
                              void* d_out, int out_size, void* d_ws, size_t ws_size,
                              hipStream_t stream) {
    const float* key   = (const float*)d_in[0];
    const float* value = (const float*)d_in[1];
    const float* query = (const float*)d_in[2];
    const int*   mask  = (const int*)d_in[3];
    const float* Wq  = (const float*)d_in[4];
    const float* bq  = (const float*)d_in[5];
    const float* Wk  = (const float*)d_in[6];
    const float* bk  = (const float*)d_in[7];
    const float* Wv  = (const float*)d_in[8];
    const float* bv  = (const float*)d_in[9];
    const float* Wcq = (const float*)d_in[10];
    const float* Wck = (const float*)d_in[11];
    const float* Wcv = (const float*)d_in[12];
    const float* Wgq = (const float*)d_in[13];
    const float* bgq = (const float*)d_in[14];
    const float* Wgk = (const float*)d_in[15];
    const float* bgk = (const float*)d_in[16];
    const float* Wgv = (const float*)d_in[17];
    const float* bgv = (const float*)d_in[18];
    const float* WmD = (const float*)d_in[19];
    const float* bmD = (const float*)d_in[20];
    const float* rpe = (const float*)d_in[21];
    const float* Wo  = (const float*)d_in[22];
    const float* bo  = (const float*)d_in[23];
    float* out = (float*)d_out;

    const size_t NTOK = (size_t)NB * NT;            // 8192
    const size_t NE   = NTOK * NSZ;                 // 4,194,304
    const size_t NW   = (size_t)NSZ * NSZ;          // 262,144

    unsigned short* ws16 = (unsigned short*)d_ws;
    unsigned short* qx  = ws16;                     // bf16 inputs
    unsigned short* kx  = qx + NE;
    unsigned short* vx  = kx + NE;
    unsigned short* qp  = vx + NE;                  // bf16 projections (gated in-place)
    unsigned short* kp  = qp + NE;
    unsigned short* vp  = kp + NE;
    unsigned short* wqh = vp + NE;
    unsigned short* wkh = wqh + NW;
    unsigned short* wvh = wkh + NW;
    unsigned short* woh = wvh + NW;
    unsigned short* cxh = woh + NW;                 // bf16 ctx
    float* mDb = (float*)(cxh + NE);

    // converts
    cvt3_bf16<<<dim3((unsigned)(NE/8/256), 3), 256, 0, stream>>>(
        query, key, value, qx, kx, vx, (int)NE);
    cvt4_bf16<<<dim3((unsigned)(NW/8/256), 4), 256, 0, stream>>>(
        Wq, Wk, Wv, Wo, wqh, wkh, wvh, woh, (int)NW);

    // projections (bf16 out)
    dim3 gg(NTOK / 128, NSZ / 128);
    gemm_mfma<true><<<gg, 256, 0, stream>>>(qx, wqh, bq, qp, (int)NTOK, NSZ, NSZ);
    gemm_mfma<true><<<gg, 256, 0, stream>>>(kx, wkh, bk, kp, (int)NTOK, NSZ, NSZ);
    gemm_mfma<true><<<gg, 256, 0, stream>>>(vx, wvh, bv, vp, (int)NTOK, NSZ, NSZ);

    // conv + gate (bf16 in-place)
    conv_gate<true ><<<(int)NTOK, 128, 0, stream>>>(kx, qp, Wcq, Wgq, bgq, WmD, bmD, mDb);
    conv_gate<false><<<(int)NTOK, 128, 0, stream>>>(kx, kp, Wck, Wgk, bgk, nullptr, nullptr, nullptr);
    conv_gate<false><<<(int)NTOK, 128, 0, stream>>>(kx, vp, Wcv, Wgv, bgv, nullptr, nullptr, nullptr);

    // attention
    dim3 ga(NT / 64, NH, NB);
    attn_tiled<<<ga, 256, 0, stream>>>(qp, kp, vp, mDb, mask, rpe, cxh);

    // output projection (fp32 out)
    gemm_mfma<false><<<gg, 256, 0, stream>>>(cxh, woh, bo, out, (int)NTOK, NSZ, NSZ);
}

// Round 6
// 189.674 us; speedup vs baseline: 7.7598x; 1.8284x over previous
//
#include <hip/hip_runtime.h>
#include <math.h>

#define NB 16
#define NT 512
#define NSZ 512
#define NH 8
#define NHD 64
#define MAXR 16

#define C_D0 6.3f
#define C_STD 1.4f
#define C_GAMMA 2.0f

#define NEGINF (-1e30f)
#define LOG2E 1.4426950408889634f
#define C1F   0.18033688011112042f   // 0.125 * log2(e)

typedef unsigned short u16;
typedef __attribute__((ext_vector_type(8))) short bf16x8;
typedef __attribute__((ext_vector_type(4))) float f32x4;
typedef __attribute__((ext_vector_type(8))) unsigned short u16x8;

__device__ __forceinline__ u16 f2b(float f) {
    union { float f; unsigned int u; } c; c.f = f;
    unsigned int u = c.u + 0x7FFFu + ((c.u >> 16) & 1u);
    return (u16)(u >> 16);
}
__device__ __forceinline__ float b2f(u16 h) {
    union { unsigned int u; float f; } c; c.u = ((unsigned int)h) << 16;
    return c.f;
}

#if __has_builtin(__builtin_amdgcn_exp2f)
__device__ __forceinline__ float exp2_fast(float x) { return __builtin_amdgcn_exp2f(x); }
#else
__device__ __forceinline__ float exp2_fast(float x) { return exp2f(x); }
#endif

#define GL2LDS(gp, lp) __builtin_amdgcn_global_load_lds( \
    (const __attribute__((address_space(1))) void*)(gp), \
    (__attribute__((address_space(3))) void*)(lp), 16, 0, 0)

// swizzled u16-index of 16B chunk c in row r (row = 8 chunks = 64 bf16)
#define SWU(r, c) ((((r) * 8) + ((c) ^ ((r) & 7))) * 8)

// ---------------------------------------------------------------------------
// fp32 -> bf16 converts
// ---------------------------------------------------------------------------
__global__ __launch_bounds__(256) void cvt3_bf16(
    const float* __restrict__ s0, const float* __restrict__ s1,
    const float* __restrict__ s2, u16* __restrict__ d0,
    u16* __restrict__ d1, u16* __restrict__ d2, int n)
{
    const float* s = blockIdx.y == 0 ? s0 : (blockIdx.y == 1 ? s1 : s2);
    u16* d = blockIdx.y == 0 ? d0 : (blockIdx.y == 1 ? d1 : d2);
    int i = (blockIdx.x * 256 + threadIdx.x) * 8;
    if (i >= n) return;
    float4 a = *(const float4*)&s[i];
    float4 b = *(const float4*)&s[i + 4];
    u16x8 v;
    v[0]=f2b(a.x); v[1]=f2b(a.y); v[2]=f2b(a.z); v[3]=f2b(a.w);
    v[4]=f2b(b.x); v[5]=f2b(b.y); v[6]=f2b(b.z); v[7]=f2b(b.w);
    *(u16x8*)&d[i] = v;
}

__global__ __launch_bounds__(256) void cvt4_bf16(
    const float* __restrict__ s0, const float* __restrict__ s1,
    const float* __restrict__ s2, const float* __restrict__ s3,
    u16* __restrict__ d0, u16* __restrict__ d1,
    u16* __restrict__ d2, u16* __restrict__ d3, int n)
{
    const float* s; u16* d;
    switch (blockIdx.y) {
        case 0: s = s0; d = d0; break;
        case 1: s = s1; d = d1; break;
        case 2: s = s2; d = d2; break;
        default: s = s3; d = d3; break;
    }
    int i = (blockIdx.x * 256 + threadIdx.x) * 8;
    if (i >= n) return;
    float4 a = *(const float4*)&s[i];
    float4 b = *(const float4*)&s[i + 4];
    u16x8 v;
    v[0]=f2b(a.x); v[1]=f2b(a.y); v[2]=f2b(a.z); v[3]=f2b(a.w);
    v[4]=f2b(b.x); v[5]=f2b(b.y); v[6]=f2b(b.z); v[7]=f2b(b.w);
    *(u16x8*)&d[i] = v;
}

__global__ void bcat_k(const float* __restrict__ bq, const float* __restrict__ bk,
                       const float* __restrict__ bv, float* __restrict__ bc)
{
    int i = blockIdx.x * 256 + threadIdx.x;
    if (i >= 1536) return;
    bc[i] = i < 512 ? bq[i] : (i < 1024 ? bk[i - 512] : bv[i - 1024]);
}

// ---------------------------------------------------------------------------
// QKV projections, z-batched (m97 structure, proven in R3)
// ---------------------------------------------------------------------------
__global__ __launch_bounds__(256) void gemm_qkv(
    const u16* __restrict__ A0, const u16* __restrict__ A1, const u16* __restrict__ A2,
    const u16* __restrict__ Wc, const float* __restrict__ bc,
    u16* __restrict__ pkv)
{
    __shared__ u16 Al[128 * 32];
    __shared__ u16 Bl[128 * 32];
    const int z = blockIdx.z;
    const u16* A = z == 0 ? A0 : (z == 1 ? A1 : A2);
    const u16* W = Wc + (size_t)z * NSZ * NSZ;
    const float* bias = bc + z * NSZ;
    const int tid = threadIdx.x;
    const int m0 = blockIdx.x * 128;
    const int n0 = blockIdx.y * 128;
    const int w = tid >> 6, lane = tid & 63;
    const int wm = (w >> 1) * 64, wn = (w & 1) * 64;
    const int fr = lane & 15, fk = lane >> 4;

    f32x4 acc[4][4] = {};
    for (int k0 = 0; k0 < NSZ; k0 += 32) {
        #pragma unroll
        for (int p = 0; p < 2; ++p) {
            int s = tid + p * 256;
            int row = s >> 2, cb = s & 3;
            GL2LDS(&A[(size_t)(m0 + row) * NSZ + k0 + cb * 8], &Al[s * 8]);
            GL2LDS(&W[(size_t)(n0 + row) * NSZ + k0 + cb * 8], &Bl[s * 8]);
        }
        __syncthreads();
        bf16x8 af[4], bfr[4];
        #pragma unroll
        for (int mf = 0; mf < 4; ++mf)
            af[mf] = *(const bf16x8*)&Al[(wm + mf * 16 + fr) * 32 + fk * 8];
        #pragma unroll
        for (int nf = 0; nf < 4; ++nf)
            bfr[nf] = *(const bf16x8*)&Bl[(wn + nf * 16 + fr) * 32 + fk * 8];
        #pragma unroll
        for (int mf = 0; mf < 4; ++mf)
            #pragma unroll
            for (int nf = 0; nf < 4; ++nf)
                acc[mf][nf] = __builtin_amdgcn_mfma_f32_16x16x32_bf16(
                    af[mf], bfr[nf], acc[mf][nf], 0, 0, 0);
        __syncthreads();
    }
    #pragma unroll
    for (int mf = 0; mf < 4; ++mf) {
        #pragma unroll
        for (int nf = 0; nf < 4; ++nf) {
            int col = n0 + wn + nf * 16 + fr;
            float bv = bias[col];
            #pragma unroll
            for (int r = 0; r < 4; ++r) {
                int rowg = m0 + wm + mf * 16 + fk * 4 + r;
                pkv[(size_t)rowg * 1536 + z * 512 + col] = f2b(acc[mf][nf][r] + bv);
            }
        }
    }
}

// ---------------------------------------------------------------------------
// Output projection (fp32 out)
// ---------------------------------------------------------------------------
__global__ __launch_bounds__(256) void gemm_out(
    const u16* __restrict__ A, const u16* __restrict__ W,
    const float* __restrict__ bias, float* __restrict__ Cout, int M, int N, int K)
{
    __shared__ u16 Al[128 * 32];
    __shared__ u16 Bl[128 * 32];
    const int tid = threadIdx.x;
    const int m0 = blockIdx.x * 128;
    const int n0 = blockIdx.y * 128;
    const int w = tid >> 6, lane = tid & 63;
    const int wm = (w >> 1) * 64, wn = (w & 1) * 64;
    const int fr = lane & 15, fk = lane >> 4;

    f32x4 acc[4][4] = {};
    for (int k0 = 0; k0 < K; k0 += 32) {
        #pragma unroll
        for (int p = 0; p < 2; ++p) {
            int s = tid + p * 256;
            int row = s >> 2, cb = s & 3;
            GL2LDS(&A[(size_t)(m0 + row) * K + k0 + cb * 8], &Al[s * 8]);
            GL2LDS(&W[(size_t)(n0 + row) * K + k0 + cb * 8], &Bl[s * 8]);
        }
        __syncthreads();
        bf16x8 af[4], bfr[4];
        #pragma unroll
        for (int mf = 0; mf < 4; ++mf)
            af[mf] = *(const bf16x8*)&Al[(wm + mf * 16 + fr) * 32 + fk * 8];
        #pragma unroll
        for (int nf = 0; nf < 4; ++nf)
            bfr[nf] = *(const bf16x8*)&Bl[(wn + nf * 16 + fr) * 32 + fk * 8];
        #pragma unroll
        for (int mf = 0; mf < 4; ++mf)
            #pragma unroll
            for (int nf = 0; nf < 4; ++nf)
                acc[mf][nf] = __builtin_amdgcn_mfma_f32_16x16x32_bf16(
                    af[mf], bfr[nf], acc[mf][nf], 0, 0, 0);
        __syncthreads();
    }
    #pragma unroll
    for (int mf = 0; mf < 4; ++mf) {
        #pragma unroll
        for (int nf = 0; nf < 4; ++nf) {
            int col = n0 + wn + nf * 16 + fr;
            float bv = bias[col];
            #pragma unroll
            for (int r = 0; r < 4; ++r) {
                int rowg = m0 + wm + mf * 16 + fk * 4 + r;
                Cout[(size_t)rowg * N + col] = acc[mf][nf][r] + bv;
            }
        }
    }
}

// ---------------------------------------------------------------------------
// Fused 3x depthwise conv1d(k=5) + 3 scalar gates + mD; pkv in-place.
// ---------------------------------------------------------------------------
__global__ __launch_bounds__(128) void conv_gate_all(
    const u16* __restrict__ xn, u16* __restrict__ pkv,
    const float* __restrict__ Wcq, const float* __restrict__ Wck, const float* __restrict__ Wcv,
    const float* __restrict__ Wgq, const float* __restrict__ bgq,
    const float* __restrict__ Wgk, const float* __restrict__ bgk,
    const float* __restrict__ Wgv, const float* __restrict__ bgv,
    const float* __restrict__ WmD, const float* __restrict__ bmD,
    float* __restrict__ mD)
{
    const int bt = blockIdx.x;
    const int b = bt / NT, tpos = bt % NT;
    const int tid = threadIdx.x;
    __shared__ float red[3][128];
    __shared__ float redm[128];

    float x5[4][5];
    #pragma unroll
    for (int i = 0; i < 4; ++i) {
        int c = tid + i * 128;
        #pragma unroll
        for (int j = 0; j < 5; ++j) {
            int tt = tpos + j - 2;
            x5[i][j] = (tt >= 0 && tt < NT) ? b2f(xn[((size_t)b*NT + tt)*NSZ + c]) : 0.f;
        }
    }
    const size_t rb = (size_t)bt * 1536;
    float qc[4], kc[4], vc[4], qp[4], kp[4], vp[4];
    float sq = 0.f, sk = 0.f, sv = 0.f;
    #pragma unroll
    for (int i = 0; i < 4; ++i) {
        int c = tid + i * 128;
        float aq = 0.f, ak = 0.f, av = 0.f;
        #pragma unroll
        for (int j = 0; j < 5; ++j) {
            aq += x5[i][j] * Wcq[c*5 + j];
            ak += x5[i][j] * Wck[c*5 + j];
            av += x5[i][j] * Wcv[c*5 + j];
        }
        qc[i] = aq; kc[i] = ak; vc[i] = av;
        qp[i] = b2f(pkv[rb + c]);
        kp[i] = b2f(pkv[rb + 512 + c]);
        vp[i] = b2f(pkv[rb + 1024 + c]);
        sq += qp[i] * Wgq[c] + aq * Wgq[512 + c];
        sk += kp[i] * Wgk[c] + ak * Wgk[512 + c];
        sv += vp[i] * Wgv[c] + av * Wgv[512 + c];
    }
    red[0][tid] = sq; red[1][tid] = sk; red[2][tid] = sv;
    __syncthreads();
    for (int st = 64; st > 0; st >>= 1) {
        if (tid < st) {
            red[0][tid] += red[0][tid + st];
            red[1][tid] += red[1][tid + st];
            red[2][tid] += red[2][tid + st];
        }
        __syncthreads();
    }
    float gq = 1.f / (1.f + expf(-(red[0][0] + bgq[0])));
    float gk = 1.f / (1.f + expf(-(red[1][0] + bgk[0])));
    float gv = 1.f / (1.f + expf(-(red[2][0] + bgv[0])));
    float smd = 0.f;
    #pragma unroll
    for (int i = 0; i < 4; ++i) {
        int c = tid + i * 128;
        float oq = (1.f - gq) * qp[i] + gq * qc[i];
        pkv[rb + c]        = f2b(oq);
        pkv[rb + 512 + c]  = f2b((1.f - gk) * kp[i] + gk * kc[i]);
        pkv[rb + 1024 + c] = f2b((1.f - gv) * vp[i] + gv * vc[i]);
        smd += oq * WmD[c];
    }
    redm[tid] = smd; __syncthreads();
    for (int st = 64; st > 0; st >>= 1) {
        if (tid < st) redm[tid] += redm[tid + st];
        __syncthreads();
    }
    if (tid == 0)
        mD[bt] = C_D0 + 2.f * C_STD * tanhf((redm[0] + bmD[0]) / C_GAMMA);
}

// ---------------------------------------------------------------------------
// V transpose: pkv v-section (b,t,h*64+d) -> vpT[(b*8+h)*64+d][t]
// ---------------------------------------------------------------------------
__global__ __launch_bounds__(256) void vtrans(
    const u16* __restrict__ pkv, u16* __restrict__ vpT)
{
    __shared__ u16 lt[64][72];
    const int t0 = blockIdx.x * 64;
    const int h = blockIdx.y, b = blockIdx.z;
    const int tid = threadIdx.x;
    #pragma unroll
    for (int p = 0; p < 2; ++p) {
        int s = tid + p * 256;
        int t = s >> 3, c8 = s & 7;
        u16x8 v = *(const u16x8*)&pkv[((size_t)(b*NT + t0 + t))*1536 + 1024 + h*NHD + c8*8];
        *(u16x8*)&lt[t][c8 * 8] = v;
    }
    __syncthreads();
    #pragma unroll
    for (int p = 0; p < 2; ++p) {
        int s = tid + p * 256;
        int d = s >> 3, c8 = s & 7;
        u16x8 o;
        #pragma unroll
        for (int j = 0; j < 8; ++j) o[j] = lt[c8 * 8 + j][d];
        *(u16x8*)&vpT[((size_t)((b*NH + h)*NHD + d))*NT + t0 + c8*8] = o;
    }
}

// ---------------------------------------------------------------------------
// MFMA flash attention — defensive sync version.
// FIX vs R4/R5: rpe staging loops are tid-strided (264 chunks > 256 threads;
// the one-shot `if (tid < 264)` left rpk/rvl row 32 (the rd=32 tail bucket)
// uninitialized -> NaN garbage fed the qdr MFMA). Zero-fill now actually runs.
// ---------------------------------------------------------------------------
__global__ __launch_bounds__(256) void attn_mfma(
    const u16* __restrict__ pkv, const u16* __restrict__ vpT,
    const float* __restrict__ mD, const int* __restrict__ mask,
    const float* __restrict__ rpe, u16* __restrict__ cxh)
{
    __shared__ __align__(16) char smem[73472];
    u16*  Ql    = (u16*)(smem);              // 64x64 swz
    u16*  Kl    = (u16*)(smem + 8192);       // [2][64x64] swz (rows = k)
    u16*  Vl    = (u16*)(smem + 24576);      // [2][64x64] swz (rows = d)
    u16*  Pl    = (u16*)(smem + 40960);      // 64x64 swz / linear bounce
    u16*  rpk   = (u16*)(smem + 49152);      // [48][64] swz (rows 33..47 zero)
    float* qdrl = (float*)(smem + 55296);    // [64][36]
    float* wbufl= (float*)(smem + 64512);    // [64][34]
    float* inv2s= (float*)(smem + 73216);    // [64]
    float* rvl  = (float*)(smem + 8192);     // alias Kl (epilogue): [33][64]

    const int tid  = threadIdx.x;
    const int lane = tid & 63;
    const int w    = tid >> 6;
    const int wq0  = w * 16;
    const int fr   = lane & 15;
    const int fq   = lane >> 4;
    const int b    = blockIdx.x >> 3;
    const int h    = blockIdx.x & 7;
    const int q0   = blockIdx.y * 64;

    const size_t qbase  = ((size_t)(b*NT + q0)) * 1536 + h * NHD;
    const size_t kbaseg = ((size_t)b * NT) * 1536 + 512 + h * NHD;
    const size_t vbaseg = ((size_t)((b*NH + h) * NHD)) * NT;

    // ---- prologue: reg-load Q, K0, V0; swizzled ds_write ----
    int r_[2], cs_[2];
    u16x8 qreg[2], kreg[2], vreg[2];
    #pragma unroll
    for (int p = 0; p < 2; ++p) {
        int s = tid + p * 256;
        r_[p] = s >> 3; cs_[p] = s & 7;
        qreg[p] = *(const u16x8*)(pkv + qbase  + (size_t)r_[p] * 1536 + cs_[p] * 8);
        kreg[p] = *(const u16x8*)(pkv + kbaseg + (size_t)r_[p] * 1536 + cs_[p] * 8);
        vreg[p] = *(const u16x8*)(vpT + vbaseg + (size_t)r_[p] * NT   + cs_[p] * 8);
    }
    #pragma unroll
    for (int p = 0; p < 2; ++p) {
        *(u16x8*)(Ql + SWU(r_[p], cs_[p])) = qreg[p];
        *(u16x8*)(Kl + SWU(r_[p], cs_[p])) = kreg[p];
        *(u16x8*)(Vl + SWU(r_[p], cs_[p])) = vreg[p];
    }
    // rpe_k staging: 33 rows x 8 chunks = 264 > 256 threads -> MUST be strided
    for (int idx = tid; idx < 264; idx += 256) {
        int r = idx >> 3, c = idx & 7;
        float4 f0 = *(const float4*)&rpe[r * 128 + c * 8];
        float4 f1 = *(const float4*)&rpe[r * 128 + c * 8 + 4];
        u16x8 vv;
        vv[0]=f2b(f0.x); vv[1]=f2b(f0.y); vv[2]=f2b(f0.z); vv[3]=f2b(f0.w);
        vv[4]=f2b(f1.x); vv[5]=f2b(f1.y); vv[6]=f2b(f1.z); vv[7]=f2b(f1.w);
        *(u16x8*)(rpk + SWU(r, c)) = vv;
    }
    if (tid < 120) {   // zero rows 33..47 (15 rows x 8 chunks)
        u16x8 vv = {0,0,0,0,0,0,0,0};
        *(u16x8*)(rpk + (((33 + (tid >> 3)) * 8) + (tid & 7)) * 8) = vv;
    }
    if (tid < 64) {
        float md = mD[b * NT + q0 + tid];
        inv2s[tid] = 2.f * LOG2E / (md * md);
    }
    for (int i = tid; i < 64 * 34; i += 256) wbufl[i] = 0.f;
    int nt;
    {
        unsigned long long bal = __ballot(lane < 8 && mask[b * NT + lane * 64] != 0);
        nt = bal ? (int)__ffsll(bal) - 1 : 8;
    }
    __syncthreads();

    // persistent Q A-frags
    bf16x8 aq0 = *(const bf16x8*)(Ql + SWU(wq0 + fr, fq));
    bf16x8 aq1 = *(const bf16x8*)(Ql + SWU(wq0 + fr, 4 + fq));

    // qdr[q][rd] = q . rpe_k[rd] via MFMA
    {
        f32x4 qd[3] = {};
        #pragma unroll
        for (int nf = 0; nf < 3; ++nf) {
            bf16x8 b0 = *(const bf16x8*)(rpk + SWU(nf * 16 + fr, fq));
            bf16x8 b1 = *(const bf16x8*)(rpk + SWU(nf * 16 + fr, 4 + fq));
            qd[nf] = __builtin_amdgcn_mfma_f32_16x16x32_bf16(aq0, b0, qd[nf], 0, 0, 0);
            qd[nf] = __builtin_amdgcn_mfma_f32_16x16x32_bf16(aq1, b1, qd[nf], 0, 0, 0);
        }
        #pragma unroll
        for (int nf = 0; nf < 3; ++nf) {
            int rd = nf * 16 + fr;
            if (rd < 33) {
                #pragma unroll
                for (int r = 0; r < 4; ++r)
                    qdrl[(wq0 + fq * 4 + r) * 36 + rd] = qd[nf][r];
            }
        }
    }
    __syncthreads();

    f32x4 O[4] = {};
    float m2[4] = {NEGINF, NEGINF, NEGINF, NEGINF};
    float li[4] = {};

    for (int t = 0; t < nt; ++t) {
        const int cur = t & 1;
        const int kb = t * 64;
        u16* Kc = Kl + cur * 4096;
        u16* Vc = Vl + cur * 4096;
        const bool pre = (t + 1 < nt);
        u16x8 kreg2[2], vreg2[2];
        if (pre) {
            const int kn = (t + 1) * 64;
            #pragma unroll
            for (int p = 0; p < 2; ++p) {
                kreg2[p] = *(const u16x8*)(pkv + kbaseg + (size_t)(kn + r_[p]) * 1536 + cs_[p] * 8);
                vreg2[p] = *(const u16x8*)(vpT + vbaseg + (size_t)r_[p] * NT + kn + cs_[p] * 8);
            }
        }
        // mask for this tile: direct global loads (mask is 32KB, L2-resident)
        int mk[4];
        #pragma unroll
        for (int nf = 0; nf < 4; ++nf) mk[nf] = mask[b * NT + kb + nf * 16 + fr];

        // ---- QK^T ----
        f32x4 s_[4] = {};
        #pragma unroll
        for (int nf = 0; nf < 4; ++nf) {
            bf16x8 b0 = *(const bf16x8*)(Kc + SWU(nf * 16 + fr, fq));
            bf16x8 b1 = *(const bf16x8*)(Kc + SWU(nf * 16 + fr, 4 + fq));
            s_[nf] = __builtin_amdgcn_mfma_f32_16x16x32_bf16(aq0, b0, s_[nf], 0, 0, 0);
            s_[nf] = __builtin_amdgcn_mfma_f32_16x16x32_bf16(aq1, b1, s_[nf], 0, 0, 0);
        }
        // ---- softmax (log2 domain) ----
        const bool leftfar  = (kb + 79 <= q0);
        const bool rightfar = (kb >= q0 + 79);
        const bool mid = !leftfar && !rightfar;

        float p_[4][4], alpha[4], rsum_[4], ls_[4], rs_[4];
        #pragma unroll
        for (int r = 0; r < 4; ++r) {
            const int lq = wq0 + fq * 4 + r;
            const int qg = q0 + lq;
            const float iv = inv2s[lq];
            const float qf = leftfar ? qdrl[lq * 36] : (rightfar ? qdrl[lq * 36 + 32] : 0.f);
            float mx = NEGINF;
            #pragma unroll
            for (int nf = 0; nf < 4; ++nf) {
                const int kg = kb + nf * 16 + fr;
                float sc;
                if (mk[nf]) sc = NEGINF;
                else {
                    float qr = mid ? qdrl[lq * 36 + (min(max(kg - qg, -MAXR), MAXR) + MAXR)] : qf;
                    float fd = (float)(qg - kg);
                    sc = (s_[nf][r] + qr) * C1F - fd * fd * iv;
                }
                p_[r][nf] = sc;
                mx = fmaxf(mx, sc);
            }
            mx = fmaxf(mx, __shfl_xor(mx, 1, 64));
            mx = fmaxf(mx, __shfl_xor(mx, 2, 64));
            mx = fmaxf(mx, __shfl_xor(mx, 4, 64));
            mx = fmaxf(mx, __shfl_xor(mx, 8, 64));
            float mn = fmaxf(m2[r], mx);
            alpha[r] = exp2_fast(m2[r] - mn);
            m2[r] = mn;
            float rsum = 0.f, ls = 0.f, rs = 0.f;
            #pragma unroll
            for (int nf = 0; nf < 4; ++nf) {
                float pv = exp2_fast(p_[r][nf] - mn);
                p_[r][nf] = pv;
                rsum += pv;
                if (mid) {
                    int kg = kb + nf * 16 + fr;
                    if (kg <= qg - MAXR) ls += pv;
                    else if (kg >= qg + MAXR) rs += pv;
                }
            }
            rsum += __shfl_xor(rsum, 1, 64); rsum += __shfl_xor(rsum, 2, 64);
            rsum += __shfl_xor(rsum, 4, 64); rsum += __shfl_xor(rsum, 8, 64);
            if (mid) {
                ls += __shfl_xor(ls, 1, 64); ls += __shfl_xor(ls, 2, 64);
                ls += __shfl_xor(ls, 4, 64); ls += __shfl_xor(ls, 8, 64);
                rs += __shfl_xor(rs, 1, 64); rs += __shfl_xor(rs, 2, 64);
                rs += __shfl_xor(rs, 4, 64); rs += __shfl_xor(rs, 8, 64);
            }
            li[r] = li[r] * alpha[r] + rsum;
            rsum_[r] = rsum; ls_[r] = ls; rs_[r] = rs;
        }
        // O rescale
        #pragma unroll
        for (int nf = 0; nf < 4; ++nf) {
            O[nf][0] *= alpha[0]; O[nf][1] *= alpha[1];
            O[nf][2] *= alpha[2]; O[nf][3] *= alpha[3];
        }
        // wbuf rescale, then tile contributions
        #pragma unroll
        for (int r = 0; r < 4; ++r) {
            int lq = wq0 + fq * 4 + r;
            if (alpha[r] != 1.f) {
                for (int c = fr; c < 33; c += 16) wbufl[lq * 34 + c] *= alpha[r];
            }
        }
        if (fr == 0) {
            #pragma unroll
            for (int r = 0; r < 4; ++r) {
                int lq = wq0 + fq * 4 + r;
                if (leftfar)       wbufl[lq * 34]      += rsum_[r];
                else if (rightfar) wbufl[lq * 34 + 32] += rsum_[r];
                else { wbufl[lq * 34] += ls_[r]; wbufl[lq * 34 + 32] += rs_[r]; }
            }
        }
        if (mid) {
            #pragma unroll
            for (int r = 0; r < 4; ++r) {
                int lq = wq0 + fq * 4 + r, qg = q0 + lq;
                #pragma unroll
                for (int nf = 0; nf < 4; ++nf) {
                    int d = kb + nf * 16 + fr - qg;
                    if (d > -MAXR && d < MAXR) wbufl[lq * 34 + d + MAXR] += p_[r][nf];
                }
            }
        }
        // ---- P -> bf16 LDS (swizzled) ----
        #pragma unroll
        for (int r = 0; r < 4; ++r) {
            int lq = wq0 + fq * 4 + r;
            #pragma unroll
            for (int nf = 0; nf < 4; ++nf) {
                int k = nf * 16 + fr;
                Pl[lq * 64 + (((k >> 3) ^ (lq & 7)) << 3) + (k & 7)] = f2b(p_[r][nf]);
            }
        }
        __syncthreads();    // P visible; all QK reads of Kc done
        // ---- PV ----
        bf16x8 ap0 = *(const bf16x8*)(Pl + SWU(wq0 + fr, fq));
        bf16x8 ap1 = *(const bf16x8*)(Pl + SWU(wq0 + fr, 4 + fq));
        #pragma unroll
        for (int nf = 0; nf < 4; ++nf) {
            bf16x8 v0 = *(const bf16x8*)(Vc + SWU(nf * 16 + fr, fq));
            bf16x8 v1 = *(const bf16x8*)(Vc + SWU(nf * 16 + fr, 4 + fq));
            O[nf] = __builtin_amdgcn_mfma_f32_16x16x32_bf16(ap0, v0, O[nf], 0, 0, 0);
            O[nf] = __builtin_amdgcn_mfma_f32_16x16x32_bf16(ap1, v1, O[nf], 0, 0, 0);
        }
        // stage next tile into the other buffer (nobody reads it this iter)
        if (pre) {
            #pragma unroll
            for (int p = 0; p < 2; ++p) {
                *(u16x8*)(Kl + (1 - cur) * 4096 + SWU(r_[p], cs_[p])) = kreg2[p];
                *(u16x8*)(Vl + (1 - cur) * 4096 + SWU(r_[p], cs_[p])) = vreg2[p];
            }
        }
        __syncthreads();    // publish next tile; all done with cur + Pl
    }

    // ---- epilogue: rpe_v via wbuf buckets ----
    for (int idx = tid; idx < 264; idx += 256) {   // strided: 264 > 256
        int r = idx >> 3, c = idx & 7;
        float4 f0 = *(const float4*)&rpe[r * 128 + 64 + c * 8];
        float4 f1 = *(const float4*)&rpe[r * 128 + 64 + c * 8 + 4];
        *(float4*)(rvl + r * 64 + c * 8) = f0;
        *(float4*)(rvl + r * 64 + c * 8 + 4) = f1;
    }
    __syncthreads();
    for (int rd = 0; rd < 33; ++rd) {
        float rvv[4];
        #pragma unroll
        for (int nf = 0; nf < 4; ++nf) rvv[nf] = rvl[rd * 64 + nf * 16 + fr];
        #pragma unroll
        for (int r = 0; r < 4; ++r) {
            float wv = wbufl[(wq0 + fq * 4 + r) * 34 + rd];
            #pragma unroll
            for (int nf = 0; nf < 4; ++nf) O[nf][r] += wv * rvv[nf];
        }
    }
    float invl[4];
    #pragma unroll
    for (int r = 0; r < 4; ++r) invl[r] = 1.f / li[r];
    #pragma unroll
    for (int r = 0; r < 4; ++r) {
        int lq = wq0 + fq * 4 + r;
        #pragma unroll
        for (int nf = 0; nf < 4; ++nf)
            Pl[lq * 64 + nf * 16 + fr] = f2b(O[nf][r] * invl[r]);   // linear bounce
    }
    __syncthreads();
    #pragma unroll
    for (int j = 0; j < 2; ++j) {
        int s = w * 128 + j * 64 + lane;
        int rr = s >> 3, c8 = s & 7;
        u16x8 vv = *(const u16x8*)(Pl + rr * 64 + c8 * 8);
        *(u16x8*)&cxh[((size_t)(b*NT + q0 + rr)) * 512 + h * NHD + c8 * 8] = vv;
    }
}

// ---------------------------------------------------------------------------
extern "C" void kernel_launch(void* const* d_in, const int* in_sizes, int n_in,
                              void* d_out, int out_size, void* d_ws, size_t ws_size,
                              hipStream_t stream) {
    const float* key   = (const float*)d_in[0];
    const float* value = (const float*)d_in[1];
    const float* query = (const float*)d_in[2];
    const int*   mask  = (const int*)d_in[3];
    const float* Wq  = (const float*)d_in[4];
    const float* bq  = (const float*)d_in[5];
    const float* Wk  = (const float*)d_in[6];
    const float* bk  = (const float*)d_in[7];
    const float* Wv  = (const float*)d_in[8];
    const float* bv  = (const float*)d_in[9];
    const float* Wcq = (const float*)d_in[10];
    const float* Wck = (const float*)d_in[11];
    const float* Wcv = (const float*)d_in[12];
    const float* Wgq = (const float*)d_in[13];
    const float* bgq = (const float*)d_in[14];
    const float* Wgk = (const float*)d_in[15];
    const float* bgk = (const float*)d_in[16];
    const float* Wgv = (const float*)d_in[17];
    const float* bgv = (const float*)d_in[18];
    const float* WmD = (const float*)d_in[19];
    const float* bmD = (const float*)d_in[20];
    const float* rpe = (const float*)d_in[21];
    const float* Wo  = (const float*)d_in[22];
    const float* bo  = (const float*)d_in[23];
    float* out = (float*)d_out;

    const size_t NTOK = (size_t)NB * NT;            // 8192
    const size_t NE   = NTOK * NSZ;                 // 4,194,304
    const size_t NW   = (size_t)NSZ * NSZ;          // 262,144

    u16* ws16 = (u16*)d_ws;
    u16* qx   = ws16;                // bf16 inputs
    u16* kx   = qx + NE;
    u16* vx   = kx + NE;
    u16* pkv  = vx + NE;             // (8192, 1536) q|k|v
    u16* wcat = pkv + NTOK * 1536;   // 3 x (512,512)
    u16* woh  = wcat + 3 * NW;
    u16* vpT  = woh + NW;            // (16*8*64, 512)
    u16* cxh  = vpT + NE;            // (8192, 512)
    float* bcat = (float*)(cxh + NE);
    float* mDb  = bcat + 1536;

    cvt3_bf16<<<dim3((unsigned)(NE/8/256), 3), 256, 0, stream>>>(
        query, key, value, qx, kx, vx, (int)NE);
    cvt4_bf16<<<dim3((unsigned)(NW/8/256), 4), 256, 0, stream>>>(
        Wq, Wk, Wv, Wo, wcat, wcat + NW, wcat + 2*NW, woh, (int)NW);
    bcat_k<<<6, 256, 0, stream>>>(bq, bk, bv, bcat);

    gemm_qkv<<<dim3(64, 4, 3), 256, 0, stream>>>(qx, kx, vx, wcat, bcat, pkv);

    conv_gate_all<<<(int)NTOK, 128, 0, stream>>>(
        kx, pkv, Wcq, Wck, Wcv, Wgq, bgq, Wgk, bgk, Wgv, bgv, WmD, bmD, mDb);

    vtrans<<<dim3(8, 8, 16), 256, 0, stream>>>(pkv, vpT);

    attn_mfma<<<dim3(128, 8), 256, 0, stream>>>(pkv, vpT, mDb, mask, rpe, cxh);

    gemm_out<<<dim3(64, 4), 256, 0, stream>>>(cxh, woh, bo, out, (int)NTOK, NSZ, NSZ);
}